// Round 3
// baseline (5218.641 us; speedup 1.0000x reference)
//
#include <hip/hip_runtime.h>

// Chamfer distance via exact uniform-grid nearest-neighbor search.
// Grid: 128^3 cells, h=0.1, origin -6.4 (covers N(0,1) clouds; edges clamped,
// which is exact: a clamped cell's unbounded extension is farther, not closer).
// Per direction: bin+sort reference cloud by cell, then per query expand
// Chebyshev shells; stop when ((R-1)h)^2 >= best. Row/cell pruning by exact
// axis distance. Distance form: |y|^2 - 2 q.y (fma chain), + |q|^2 at end --
// identical arithmetic to the R2 brute-force kernel (absmax was 0.0).

#define G 128
#define GSH 7
#define CCELLS (G * G * G)            // 2097152
#define H 0.1f
#define INVH 10.0f
#define ORIG (-6.4f)
#define NCHUNK (CCELLS / 256)         // 8192

__device__ __forceinline__ int cellcoord(float x) {
    int c = (int)floorf((x - ORIG) * INVH);
    return min(max(c, 0), G - 1);
}
__device__ __forceinline__ int cellof(float x, float y, float z) {
    return (cellcoord(z) << (2 * GSH)) + (cellcoord(y) << GSH) + cellcoord(x);
}
__device__ __forceinline__ float axdist(int u, float qc) {
    float lo = ORIG + u * H;
    return fmaxf(0.0f, fmaxf(lo - qc, qc - (lo + H)));
}

// ---- build pipeline ----
__global__ __launch_bounds__(256) void hist_kernel(
    const float4* __restrict__ in, unsigned int* __restrict__ counts, int n) {
    int i = blockIdx.x * 256 + threadIdx.x;
    if (i < n) {
        float4 a = in[i];
        atomicAdd(&counts[cellof(a.x, a.y, a.z)], 1u);
    }
}

__global__ __launch_bounds__(256) void scan_chunk_kernel(
    const unsigned int* __restrict__ counts, unsigned int* __restrict__ excl,
    unsigned int* __restrict__ blockSums) {
    __shared__ unsigned int lds[256];
    int g = blockIdx.x * 256 + threadIdx.x;
    unsigned int v = counts[g];
    lds[threadIdx.x] = v;
    __syncthreads();
    for (int off = 1; off < 256; off <<= 1) {
        unsigned int t = (threadIdx.x >= off) ? lds[threadIdx.x - off] : 0u;
        __syncthreads();
        lds[threadIdx.x] += t;
        __syncthreads();
    }
    excl[g] = lds[threadIdx.x] - v;
    if (threadIdx.x == 255) blockSums[blockIdx.x] = lds[255];
}

__global__ __launch_bounds__(256) void scan_sums_kernel(
    unsigned int* __restrict__ bs) {
    __shared__ unsigned int lds[256];
    int t = threadIdx.x;
    unsigned int s = 0;
#pragma unroll 4
    for (int k = 0; k < NCHUNK / 256; ++k) s += bs[t * (NCHUNK / 256) + k];
    lds[t] = s;
    __syncthreads();
    for (int off = 1; off < 256; off <<= 1) {
        unsigned int u = (t >= off) ? lds[t - off] : 0u;
        __syncthreads();
        lds[t] += u;
        __syncthreads();
    }
    unsigned int run = lds[t] - s;  // exclusive chunk offset
    for (int k = 0; k < NCHUNK / 256; ++k) {
        unsigned int v = bs[t * (NCHUNK / 256) + k];
        bs[t * (NCHUNK / 256) + k] = run;
        run += v;
    }
}

__global__ __launch_bounds__(256) void add_offsets_kernel(
    unsigned int* __restrict__ excl, const unsigned int* __restrict__ bs, int n) {
    int g = blockIdx.x * 256 + threadIdx.x;
    excl[g] += bs[blockIdx.x];
    if (g == 0) excl[CCELLS] = (unsigned int)n;
}

__global__ __launch_bounds__(256) void scatter_kernel(
    const float4* __restrict__ in, unsigned int* __restrict__ next,
    float4* __restrict__ out, int n) {
    int i = blockIdx.x * 256 + threadIdx.x;
    if (i < n) {
        float4 a = in[i];
        unsigned int slot = atomicAdd(&next[cellof(a.x, a.y, a.z)], 1u);
        float s = fmaf(a.x, a.x, fmaf(a.y, a.y, a.z * a.z));
        out[slot] = make_float4(a.x, a.y, a.z, s);
    }
}

// ---- query ----
__global__ __launch_bounds__(256) void nn_query_kernel(
    const float4* __restrict__ Q, int nq,
    const unsigned int* __restrict__ start, const float4* __restrict__ pts,
    double* __restrict__ acc) {
    int i = blockIdx.x * 256 + threadIdx.x;
    float v = 0.0f;
    if (i < nq) {
        float4 q = Q[i];
        float nx = -2.0f * q.x, ny = -2.0f * q.y, nz = -2.0f * q.z;
        float q2 = q.w;
        int qx = cellcoord(q.x), qy = cellcoord(q.y), qz = cellcoord(q.z);
        float best = 3.4e38f;  // relative: min(|y|^2 - 2 q.y); abs = q2 + best
        for (int R = 0; R < G; ++R) {
            if (R > 0) {
                float b = (float)(R - 1) * H;
                if (b * b >= q2 + best) break;
            }
            int z0 = max(qz - R, 0), z1 = min(qz + R, G - 1);
            for (int uz = z0; uz <= z1; ++uz) {
                int az = uz > qz ? uz - qz : qz - uz;
                float dz = axdist(uz, q.z);
                int y0 = max(qy - R, 0), y1 = min(qy + R, G - 1);
                for (int uy = y0; uy <= y1; ++uy) {
                    int ay = uy > qy ? uy - qy : qy - uy;
                    float dy = axdist(uy, q.y);
                    float rowd2 = fmaf(dz, dz, dy * dy);
                    if (rowd2 >= q2 + best) continue;
                    unsigned int base = ((unsigned)uz << (2 * GSH)) + ((unsigned)uy << GSH);
                    if (az == R || ay == R) {
                        // whole row is new at this ring: one contiguous run
                        int x0 = max(qx - R, 0), x1 = min(qx + R, G - 1);
                        unsigned int s = start[base + x0], e = start[base + x1 + 1];
                        for (unsigned int k = s; k < e; ++k) {
                            float4 y = pts[k];
                            float ev = fmaf(nx, y.x, fmaf(ny, y.y, fmaf(nz, y.z, y.w)));
                            best = fminf(best, ev);
                        }
                    } else {
                        // only ux = qx +/- R are new
#pragma unroll
                        for (int t = 0; t < 2; ++t) {
                            int ux = t == 0 ? qx - R : qx + R;
                            if (ux < 0 || ux > G - 1) continue;
                            float dxx = axdist(ux, q.x);
                            if (fmaf(dxx, dxx, rowd2) >= q2 + best) continue;
                            unsigned int s = start[base + ux], e = start[base + ux + 1];
                            for (unsigned int k = s; k < e; ++k) {
                                float4 y = pts[k];
                                float ev = fmaf(nx, y.x, fmaf(ny, y.y, fmaf(nz, y.z, y.w)));
                                best = fminf(best, ev);
                            }
                        }
                    }
                }
            }
        }
        v = q2 + best;  // actual min squared distance
    }
    for (int off = 32; off > 0; off >>= 1) v += __shfl_down(v, off);
    __shared__ float partial[4];
    int lane = threadIdx.x & 63, wid = threadIdx.x >> 6;
    if (lane == 0) partial[wid] = v;
    __syncthreads();
    if (threadIdx.x == 0)
        atomicAdd(acc, (double)((partial[0] + partial[1]) + (partial[2] + partial[3])));
}

__global__ void finalize_kernel(const double* __restrict__ acc,
                                float* __restrict__ out, int n) {
    out[0] = (float)(acc[0] / (double)n);
}

// ---- fallback: R2 brute-force (proven) ----
#define SPLIT 16
#define PTS 4
__global__ __launch_bounds__(256) void pack_kernel(
    const float4* __restrict__ in, float4* __restrict__ out, int n) {
    int i = blockIdx.x * 256 + threadIdx.x;
    if (i < n) {
        float4 a = in[i];
        float s = fmaf(a.x, a.x, fmaf(a.y, a.y, a.z * a.z));
        out[i] = make_float4(a.x, a.y, a.z, s);
    }
}
__device__ __forceinline__ unsigned int enc_f32(float f) {
    unsigned int u = __float_as_uint(f);
    return (u & 0x80000000u) ? ~u : (u | 0x80000000u);
}
__device__ __forceinline__ float dec_f32(unsigned int u) {
    u = (u & 0x80000000u) ? (u ^ 0x80000000u) : ~u;
    return __uint_as_float(u);
}
__global__ __launch_bounds__(256) void chamfer_dir_kernel(
    const float4* __restrict__ X, const float4* __restrict__ Y,
    int m, unsigned int* __restrict__ mins) {
    int base = blockIdx.x * (256 * PTS) + threadIdx.x;
    float x2x[PTS], x2y[PTS], x2z[PTS], xw[PTS], mn[PTS];
#pragma unroll
    for (int p = 0; p < PTS; ++p) {
        float4 x = X[base + p * 256];
        x2x[p] = -2.0f * x.x; x2y[p] = -2.0f * x.y; x2z[p] = -2.0f * x.z;
        xw[p] = x.w; mn[p] = 3.4e38f;
    }
    int seglen = m / SPLIT, j0 = blockIdx.y * seglen, j1 = j0 + seglen;
    for (int j = j0; j < j1; j += 8) {
#pragma unroll
        for (int u = 0; u < 8; u += 2) {
            float4 ya = Y[j + u];
            float4 yb = Y[j + u + 1];
#pragma unroll
            for (int p = 0; p < PTS; ++p) {
                float ea = fmaf(x2x[p], ya.x, fmaf(x2y[p], ya.y, fmaf(x2z[p], ya.z, ya.w)));
                float eb = fmaf(x2x[p], yb.x, fmaf(x2y[p], yb.y, fmaf(x2z[p], yb.z, yb.w)));
                mn[p] = fminf(fminf(mn[p], ea), eb);
            }
        }
    }
#pragma unroll
    for (int p = 0; p < PTS; ++p)
        atomicMin(&mins[base + p * 256], enc_f32(xw[p] + mn[p]));
}
__global__ __launch_bounds__(256) void reduce_kernel(
    const unsigned int* __restrict__ mins, int total, double* __restrict__ acc) {
    float s = 0.0f;
    for (int i = blockIdx.x * 256 + threadIdx.x; i < total; i += gridDim.x * 256)
        s += dec_f32(mins[i]);
    for (int off = 32; off > 0; off >>= 1) s += __shfl_down(s, off);
    __shared__ float partial[4];
    int lane = threadIdx.x & 63, wid = threadIdx.x >> 6;
    if (lane == 0) partial[wid] = s;
    __syncthreads();
    if (threadIdx.x == 0)
        atomicAdd(acc, (double)((partial[0] + partial[1]) + (partial[2] + partial[3])));
}

extern "C" void kernel_launch(void* const* d_in, const int* in_sizes, int n_in,
                              void* d_out, int out_size, void* d_ws, size_t ws_size,
                              hipStream_t stream) {
    const float4* pred = (const float4*)d_in[0];
    const float4* targ = (const float4*)d_in[1];
    float* out = (float*)d_out;
    int n = in_sizes[0] / 4;  // 131072 points
    int nblk = (n + 255) / 256;

    char* ws = (char*)d_ws;
    double* acc = (double*)ws;
    hipMemsetAsync(acc, 0, sizeof(double), stream);

    size_t startB = ((size_t)(CCELLS + 1) * 4 + 63) & ~(size_t)63;  // 8388672
    size_t nextB = (size_t)CCELLS * 4;                              // 8388608
    size_t ptsB = (size_t)131072 * 16;                              // 2097152
    size_t perCloud = startB + nextB + ptsB;
    size_t needGrid = 64 + 2 * perCloud + (size_t)NCHUNK * 4;

    if (ws_size >= needGrid && n == 131072) {
        char* p = ws + 64;
        unsigned int* startP = (unsigned int*)p;           p += startB;
        unsigned int* nextP = (unsigned int*)p;            p += nextB;
        float4* sortedP = (float4*)p;                      p += ptsB;
        unsigned int* startT = (unsigned int*)p;           p += startB;
        unsigned int* nextT = (unsigned int*)p;            p += nextB;
        float4* sortedT = (float4*)p;                      p += ptsB;
        unsigned int* blockSums = (unsigned int*)p;

        // build P grid
        hipMemsetAsync(nextP, 0, (size_t)CCELLS * 4, stream);
        hist_kernel<<<nblk, 256, 0, stream>>>(pred, nextP, n);
        scan_chunk_kernel<<<NCHUNK, 256, 0, stream>>>(nextP, startP, blockSums);
        scan_sums_kernel<<<1, 256, 0, stream>>>(blockSums);
        add_offsets_kernel<<<NCHUNK, 256, 0, stream>>>(startP, blockSums, n);
        hipMemcpyAsync(nextP, startP, (size_t)CCELLS * 4, hipMemcpyDeviceToDevice, stream);
        scatter_kernel<<<nblk, 256, 0, stream>>>(pred, nextP, sortedP, n);

        // build T grid
        hipMemsetAsync(nextT, 0, (size_t)CCELLS * 4, stream);
        hist_kernel<<<nblk, 256, 0, stream>>>(targ, nextT, n);
        scan_chunk_kernel<<<NCHUNK, 256, 0, stream>>>(nextT, startT, blockSums);
        scan_sums_kernel<<<1, 256, 0, stream>>>(blockSums);
        add_offsets_kernel<<<NCHUNK, 256, 0, stream>>>(startT, blockSums, n);
        hipMemcpyAsync(nextT, startT, (size_t)CCELLS * 4, hipMemcpyDeviceToDevice, stream);
        scatter_kernel<<<nblk, 256, 0, stream>>>(targ, nextT, sortedT, n);

        // queries (both directions), sorted order for wave coherence
        nn_query_kernel<<<nblk, 256, 0, stream>>>(sortedP, n, startT, sortedT, acc);
        nn_query_kernel<<<nblk, 256, 0, stream>>>(sortedT, n, startP, sortedP, acc);
    } else {
        // fallback: proven brute force
        size_t needBF = 64 + 2ull * n * sizeof(float4) + 2ull * n * sizeof(unsigned int);
        if (ws_size >= needBF && (n % (256 * PTS)) == 0 && (n % SPLIT) == 0) {
            float4* P = (float4*)(ws + 64);
            float4* T = P + n;
            unsigned int* minPT = (unsigned int*)(T + n);
            pack_kernel<<<nblk, 256, 0, stream>>>(pred, P, n);
            pack_kernel<<<nblk, 256, 0, stream>>>(targ, T, n);
            hipMemsetAsync(minPT, 0xFF, 2ull * n * sizeof(unsigned int), stream);
            dim3 grid(n / (256 * PTS), SPLIT);
            chamfer_dir_kernel<<<grid, 256, 0, stream>>>(P, T, n, minPT);
            chamfer_dir_kernel<<<grid, 256, 0, stream>>>(T, P, n, minPT + n);
            reduce_kernel<<<256, 256, 0, stream>>>(minPT, 2 * n, acc);
        }
    }
    finalize_kernel<<<1, 1, 0, stream>>>(acc, out, n);
}

// Round 4
// 256.930 us; speedup vs baseline: 20.3115x; 20.3115x over previous
//
#include <hip/hip_runtime.h>

// Chamfer distance via exact uniform-grid NN search, two-phase queries.
// Grid: 128^3 cells, h=0.1, origin -6.4. Pass1: thread/query scans 27-cell
// neighborhood; exact-final iff best <= h^2 (ring>=2 cells are >= h away).
// Pass2: wave/query geometric-doubling box scan for the ~6% stragglers.
// Distance: |y|^2 - 2 q.y (fma chain) + |q|^2 at end (same arithmetic as the
// R2 brute force that scored absmax 0.0).

#define G 128
#define GSH 7
#define CCELLS (G * G * G)      // 2097152
#define H 0.1f
#define INVH 10.0f
#define ORIG (-6.4f)
#define NCHUNK (CCELLS / 256)   // 8192 (= 2^13)
#define SSTRIDE 2097168u        // ((CCELLS+1)*4 + 63 & ~63) / 4  (uints)

__device__ __forceinline__ int cellcoord(float x) {
    int c = (int)floorf((x - ORIG) * INVH);
    return min(max(c, 0), G - 1);
}
__device__ __forceinline__ int cellof(float x, float y, float z) {
    return (cellcoord(z) << (2 * GSH)) + (cellcoord(y) << GSH) + cellcoord(x);
}
__device__ __forceinline__ float axdist(int u, float qc) {
    float lo = ORIG + u * H;
    return fmaxf(0.0f, fmaxf(lo - qc, qc - (lo + H)));
}

// ---- build pipeline (dual-cloud dispatches) ----
__global__ __launch_bounds__(256) void hist2_kernel(
    const float4* __restrict__ A, const float4* __restrict__ B,
    unsigned int* __restrict__ counts, int n) {
    int i = blockIdx.x * 256 + threadIdx.x;
    const float4* in = blockIdx.y ? B : A;
    unsigned int* c = counts + blockIdx.y * CCELLS;
    if (i < n) {
        float4 a = in[i];
        atomicAdd(&c[cellof(a.x, a.y, a.z)], 1u);
    }
}

__global__ __launch_bounds__(256) void scan_chunk2_kernel(
    const unsigned int* __restrict__ counts, unsigned int* __restrict__ excl,
    unsigned int* __restrict__ blockSums) {
    __shared__ unsigned int lds[256];
    int cb = blockIdx.x & (NCHUNK - 1);
    int b = blockIdx.x >> 13;
    int g = cb * 256 + threadIdx.x;
    unsigned int v = counts[b * CCELLS + g];
    lds[threadIdx.x] = v;
    __syncthreads();
    for (int off = 1; off < 256; off <<= 1) {
        unsigned int t = (threadIdx.x >= off) ? lds[threadIdx.x - off] : 0u;
        __syncthreads();
        lds[threadIdx.x] += t;
        __syncthreads();
    }
    excl[b * SSTRIDE + g] = lds[threadIdx.x] - v;
    if (threadIdx.x == 255) blockSums[blockIdx.x] = lds[255];
}

__global__ __launch_bounds__(256) void scan_sums2_kernel(
    unsigned int* __restrict__ bs0) {
    unsigned int* bs = bs0 + blockIdx.x * NCHUNK;
    __shared__ unsigned int lds[256];
    int t = threadIdx.x;
    unsigned int s = 0;
    for (int k = 0; k < NCHUNK / 256; ++k) s += bs[t * (NCHUNK / 256) + k];
    lds[t] = s;
    __syncthreads();
    for (int off = 1; off < 256; off <<= 1) {
        unsigned int u = (t >= off) ? lds[t - off] : 0u;
        __syncthreads();
        lds[t] += u;
        __syncthreads();
    }
    unsigned int run = lds[t] - s;
    for (int k = 0; k < NCHUNK / 256; ++k) {
        unsigned int v = bs[t * (NCHUNK / 256) + k];
        bs[t * (NCHUNK / 256) + k] = run;
        run += v;
    }
}

__global__ __launch_bounds__(256) void add_offsets2_kernel(
    unsigned int* __restrict__ excl, const unsigned int* __restrict__ bs, int n) {
    int cb = blockIdx.x & (NCHUNK - 1);
    int b = blockIdx.x >> 13;
    int g = cb * 256 + threadIdx.x;
    excl[b * SSTRIDE + g] += bs[blockIdx.x];
    if (g == 0) excl[b * SSTRIDE + CCELLS] = (unsigned int)n;
}

__global__ __launch_bounds__(256) void copynext2_kernel(
    const unsigned int* __restrict__ excl, unsigned int* __restrict__ next) {
    int cb = blockIdx.x & (NCHUNK - 1);
    int b = blockIdx.x >> 13;
    int g = cb * 256 + threadIdx.x;
    next[b * CCELLS + g] = excl[b * SSTRIDE + g];
}

__global__ __launch_bounds__(256) void scatter2_kernel(
    const float4* __restrict__ A, const float4* __restrict__ B,
    unsigned int* __restrict__ next, float4* __restrict__ sorted, int n) {
    int i = blockIdx.x * 256 + threadIdx.x;
    const float4* in = blockIdx.y ? B : A;
    unsigned int* nx = next + blockIdx.y * CCELLS;
    float4* out = sorted + blockIdx.y * n;
    if (i < n) {
        float4 a = in[i];
        unsigned int slot = atomicAdd(&nx[cellof(a.x, a.y, a.z)], 1u);
        float s = fmaf(a.x, a.x, fmaf(a.y, a.y, a.z * a.z));
        out[slot] = make_float4(a.x, a.y, a.z, s);
    }
}

// ---- pass 1: 27-cell neighborhood, uniform control ----
__global__ __launch_bounds__(256) void nn_pass1_kernel(
    const float4* __restrict__ Q, int nq,
    const unsigned int* __restrict__ start, const float4* __restrict__ pts,
    unsigned int* __restrict__ wl, unsigned int* __restrict__ cnt,
    double* __restrict__ acc) {
    int i = blockIdx.x * 256 + threadIdx.x;
    float v = 0.0f;
    if (i < nq) {
        float4 q = Q[i];
        float cx = -2.0f * q.x, cy = -2.0f * q.y, cz = -2.0f * q.z;
        float q2 = q.w;
        int qx = cellcoord(q.x), qy = cellcoord(q.y), qz = cellcoord(q.z);
        int x0 = max(qx - 1, 0), x1 = min(qx + 1, G - 1);
        unsigned int ss[9], ee[9];
        int idx = 0;
#pragma unroll
        for (int dz = -1; dz <= 1; ++dz) {
            int uz = min(max(qz + dz, 0), G - 1);
#pragma unroll
            for (int dy = -1; dy <= 1; ++dy) {
                int uy = min(max(qy + dy, 0), G - 1);
                unsigned int base = ((unsigned)uz << (2 * GSH)) + ((unsigned)uy << GSH);
                ss[idx] = start[base + x0];
                ee[idx] = start[base + x1 + 1];
                ++idx;
            }
        }
        float best = 3.4e38f;
#pragma unroll
        for (int r = 0; r < 9; ++r) {
            unsigned int k = ss[r], e = ee[r];
            for (; k + 2 <= e; k += 2) {
                float4 ya = pts[k];
                float4 yb = pts[k + 1];
                float ea = fmaf(cx, ya.x, fmaf(cy, ya.y, fmaf(cz, ya.z, ya.w)));
                float eb = fmaf(cx, yb.x, fmaf(cy, yb.y, fmaf(cz, yb.z, yb.w)));
                best = fminf(fminf(best, ea), eb);
            }
            if (k < e) {
                float4 ya = pts[k];
                best = fminf(best, fmaf(cx, ya.x, fmaf(cy, ya.y, fmaf(cz, ya.z, ya.w))));
            }
        }
        float ba = q2 + best;
        if (ba <= H * H) {
            v = ba;  // final: no point outside ring 1 can beat h^2
        } else {
            unsigned int w = atomicAdd(cnt, 1u);
            wl[w] = (unsigned int)i;
        }
    }
    for (int off = 32; off > 0; off >>= 1) v += __shfl_down(v, off);
    __shared__ float partial[4];
    int lane = threadIdx.x & 63, wid = threadIdx.x >> 6;
    if (lane == 0) partial[wid] = v;
    __syncthreads();
    if (threadIdx.x == 0)
        atomicAdd(acc, (double)((partial[0] + partial[1]) + (partial[2] + partial[3])));
}

// ---- pass 2: one wave per unresolved query, doubling box scan ----
__global__ __launch_bounds__(256) void nn_pass2_kernel(
    const float4* __restrict__ Q,
    const unsigned int* __restrict__ start, const float4* __restrict__ pts,
    const unsigned int* __restrict__ wl, const unsigned int* __restrict__ cnt,
    double* __restrict__ acc) {
    int lane = threadIdx.x & 63;
    int gwave = (blockIdx.x * 256 + threadIdx.x) >> 6;
    int nwave = gridDim.x * 4;
    unsigned int m = *cnt;
    float wsum = 0.0f;
    for (unsigned int e = gwave; e < m; e += (unsigned int)nwave) {
        unsigned int qi = wl[e];
        float4 q = Q[qi];
        float cx = -2.0f * q.x, cy = -2.0f * q.y, cz = -2.0f * q.z;
        float q2 = q.w;
        int qx = cellcoord(q.x), qy = cellcoord(q.y), qz = cellcoord(q.z);
        float best = 3.4e38f;
        int Rb = 2;
        for (;;) {
            int z0 = max(qz - Rb, 0), z1 = min(qz + Rb, G - 1);
            int y0 = max(qy - Rb, 0), y1 = min(qy + Rb, G - 1);
            int x0 = max(qx - Rb, 0), x1 = min(qx + Rb, G - 1);
            int nyr = y1 - y0 + 1;
            int nrows = (z1 - z0 + 1) * nyr;
            float lbest = best;
            for (int r = lane; r < nrows; r += 64) {
                int uz = z0 + r / nyr;
                int uy = y0 + r % nyr;
                float dz = axdist(uz, q.z), dy = axdist(uy, q.y);
                float rowd2 = fmaf(dz, dz, dy * dy);
                if (rowd2 >= q2 + lbest) continue;
                unsigned int base = ((unsigned)uz << (2 * GSH)) + ((unsigned)uy << GSH);
                unsigned int k = start[base + x0], ke = start[base + x1 + 1];
                for (; k < ke; ++k) {
                    float4 ya = pts[k];
                    lbest = fminf(lbest,
                        fmaf(cx, ya.x, fmaf(cy, ya.y, fmaf(cz, ya.z, ya.w))));
                }
            }
            for (int off = 32; off > 0; off >>= 1)
                lbest = fminf(lbest, __shfl_xor(lbest, off));
            best = lbest;
            float bnd = (float)Rb * H;
            if (bnd * bnd >= q2 + best || Rb >= G) break;
            Rb = min(Rb * 2, G);
        }
        wsum += q2 + best;
    }
    if (lane == 0) atomicAdd(acc, (double)wsum);
}

__global__ void finalize_kernel(const double* __restrict__ acc,
                                float* __restrict__ out, int n) {
    out[0] = (float)(acc[0] / (double)n);
}

// ---- fallback: R2 brute-force (proven, absmax 0.0) ----
#define SPLIT 16
#define PTS 4
__global__ __launch_bounds__(256) void pack_kernel(
    const float4* __restrict__ in, float4* __restrict__ out, int n) {
    int i = blockIdx.x * 256 + threadIdx.x;
    if (i < n) {
        float4 a = in[i];
        float s = fmaf(a.x, a.x, fmaf(a.y, a.y, a.z * a.z));
        out[i] = make_float4(a.x, a.y, a.z, s);
    }
}
__device__ __forceinline__ unsigned int enc_f32(float f) {
    unsigned int u = __float_as_uint(f);
    return (u & 0x80000000u) ? ~u : (u | 0x80000000u);
}
__device__ __forceinline__ float dec_f32(unsigned int u) {
    u = (u & 0x80000000u) ? (u ^ 0x80000000u) : ~u;
    return __uint_as_float(u);
}
__global__ __launch_bounds__(256) void chamfer_dir_kernel(
    const float4* __restrict__ X, const float4* __restrict__ Y,
    int m, unsigned int* __restrict__ mins) {
    int base = blockIdx.x * (256 * PTS) + threadIdx.x;
    float x2x[PTS], x2y[PTS], x2z[PTS], xw[PTS], mn[PTS];
#pragma unroll
    for (int p = 0; p < PTS; ++p) {
        float4 x = X[base + p * 256];
        x2x[p] = -2.0f * x.x; x2y[p] = -2.0f * x.y; x2z[p] = -2.0f * x.z;
        xw[p] = x.w; mn[p] = 3.4e38f;
    }
    int seglen = m / SPLIT, j0 = blockIdx.y * seglen, j1 = j0 + seglen;
    for (int j = j0; j < j1; j += 8) {
#pragma unroll
        for (int u = 0; u < 8; u += 2) {
            float4 ya = Y[j + u];
            float4 yb = Y[j + u + 1];
#pragma unroll
            for (int p = 0; p < PTS; ++p) {
                float ea = fmaf(x2x[p], ya.x, fmaf(x2y[p], ya.y, fmaf(x2z[p], ya.z, ya.w)));
                float eb = fmaf(x2x[p], yb.x, fmaf(x2y[p], yb.y, fmaf(x2z[p], yb.z, yb.w)));
                mn[p] = fminf(fminf(mn[p], ea), eb);
            }
        }
    }
#pragma unroll
    for (int p = 0; p < PTS; ++p)
        atomicMin(&mins[base + p * 256], enc_f32(xw[p] + mn[p]));
}
__global__ __launch_bounds__(256) void reduce_kernel(
    const unsigned int* __restrict__ mins, int total, double* __restrict__ acc) {
    float s = 0.0f;
    for (int i = blockIdx.x * 256 + threadIdx.x; i < total; i += gridDim.x * 256)
        s += dec_f32(mins[i]);
    for (int off = 32; off > 0; off >>= 1) s += __shfl_down(s, off);
    __shared__ float partial[4];
    int lane = threadIdx.x & 63, wid = threadIdx.x >> 6;
    if (lane == 0) partial[wid] = s;
    __syncthreads();
    if (threadIdx.x == 0)
        atomicAdd(acc, (double)((partial[0] + partial[1]) + (partial[2] + partial[3])));
}

extern "C" void kernel_launch(void* const* d_in, const int* in_sizes, int n_in,
                              void* d_out, int out_size, void* d_ws, size_t ws_size,
                              hipStream_t stream) {
    const float4* pred = (const float4*)d_in[0];
    const float4* targ = (const float4*)d_in[1];
    float* out = (float*)d_out;
    int n = in_sizes[0] / 4;  // 131072 points
    int nblk = (n + 255) / 256;

    char* ws = (char*)d_ws;
    double* acc = (double*)ws;                      // [0,8)
    unsigned int* cntP = (unsigned int*)(ws + 8);   // [8,12)
    unsigned int* cntT = (unsigned int*)(ws + 12);  // [12,16)

    size_t startB = (size_t)SSTRIDE * 4;            // per-cloud padded start bytes
    size_t needGrid = 64 + 2 * startB + 2ull * CCELLS * 4 + 2ull * n * 16
                    + 2ull * NCHUNK * 4;

    if (ws_size >= needGrid && n == 131072) {
        char* p = ws + 64;
        unsigned int* startPT = (unsigned int*)p;  p += 2 * startB;
        unsigned int* nextPT = (unsigned int*)p;   p += 2ull * CCELLS * 4;
        float4* sortedPT = (float4*)p;             p += 2ull * n * 16;
        unsigned int* blockSums = (unsigned int*)p;
        unsigned int* startP = startPT;
        unsigned int* startT = startPT + SSTRIDE;
        float4* sortedP = sortedPT;
        float4* sortedT = sortedPT + n;
        unsigned int* wlP = nextPT;            // reuse: next dead after scatter
        unsigned int* wlT = nextPT + CCELLS;

        hipMemsetAsync(ws, 0, 16, stream);  // acc + cnts
        hipMemsetAsync(nextPT, 0, 2ull * CCELLS * 4, stream);
        hist2_kernel<<<dim3(nblk, 2), 256, 0, stream>>>(pred, targ, nextPT, n);
        scan_chunk2_kernel<<<2 * NCHUNK, 256, 0, stream>>>(nextPT, startPT, blockSums);
        scan_sums2_kernel<<<2, 256, 0, stream>>>(blockSums);
        add_offsets2_kernel<<<2 * NCHUNK, 256, 0, stream>>>(startPT, blockSums, n);
        copynext2_kernel<<<2 * NCHUNK, 256, 0, stream>>>(startPT, nextPT);
        scatter2_kernel<<<dim3(nblk, 2), 256, 0, stream>>>(pred, targ, nextPT, sortedPT, n);

        nn_pass1_kernel<<<nblk, 256, 0, stream>>>(sortedP, n, startT, sortedT, wlP, cntP, acc);
        nn_pass1_kernel<<<nblk, 256, 0, stream>>>(sortedT, n, startP, sortedP, wlT, cntT, acc);
        nn_pass2_kernel<<<256, 256, 0, stream>>>(sortedP, startT, sortedT, wlP, cntP, acc);
        nn_pass2_kernel<<<256, 256, 0, stream>>>(sortedT, startP, sortedP, wlT, cntT, acc);
    } else {
        hipMemsetAsync(acc, 0, sizeof(double), stream);
        size_t needBF = 64 + 2ull * n * sizeof(float4) + 2ull * n * sizeof(unsigned int);
        if (ws_size >= needBF && (n % (256 * PTS)) == 0 && (n % SPLIT) == 0) {
            float4* P = (float4*)(ws + 64);
            float4* T = P + n;
            unsigned int* minPT = (unsigned int*)(T + n);
            pack_kernel<<<nblk, 256, 0, stream>>>(pred, P, n);
            pack_kernel<<<nblk, 256, 0, stream>>>(targ, T, n);
            hipMemsetAsync(minPT, 0xFF, 2ull * n * sizeof(unsigned int), stream);
            dim3 grid(n / (256 * PTS), SPLIT);
            chamfer_dir_kernel<<<grid, 256, 0, stream>>>(P, T, n, minPT);
            chamfer_dir_kernel<<<grid, 256, 0, stream>>>(T, P, n, minPT + n);
            reduce_kernel<<<256, 256, 0, stream>>>(minPT, 2 * n, acc);
        }
    }
    finalize_kernel<<<1, 1, 0, stream>>>(acc, out, n);
}